// Round 4
// baseline (1831.802 us; speedup 1.0000x reference)
//
#include <hip/hip_runtime.h>
#include <math.h>

typedef float f32x4 __attribute__((ext_vector_type(4)));
typedef __bf16 bf16x8 __attribute__((ext_vector_type(8)));

#define LRELU_ALPHA 0.2f

// ------------------------- CSR build -------------------------
__global__ void edge_count(const int* __restrict__ rows, int* __restrict__ cnt, int E) {
    int i = blockIdx.x * 256 + threadIdx.x;
    if (i < E) atomicAdd(&cnt[rows[i]], 1);
}

__global__ __launch_bounds__(512) void scan1(const int* __restrict__ in, int* __restrict__ out,
                                             int* __restrict__ bsum, int ncnt, int nout) {
    __shared__ int s[512];
    int t = threadIdx.x;
    int i = blockIdx.x * 512 + t;
    int v = (i < ncnt) ? in[i] : 0;
    s[t] = v; __syncthreads();
    for (int o = 1; o < 512; o <<= 1) {
        int u = (t >= o) ? s[t - o] : 0;
        __syncthreads();
        s[t] += u;
        __syncthreads();
    }
    if (i < nout) out[i] = s[t] - v;               // exclusive
    if (t == 511) bsum[blockIdx.x] = s[511];       // block total
}

__global__ void scan2(int* __restrict__ b, int nb) {   // single block, nb <= 256
    __shared__ int s[256];
    int t = threadIdx.x;
    int v = (t < nb) ? b[t] : 0;
    s[t] = v; __syncthreads();
    for (int o = 1; o < 256; o <<= 1) {
        int u = (t >= o) ? s[t - o] : 0;
        __syncthreads();
        s[t] += u;
        __syncthreads();
    }
    if (t < nb) b[t] = s[t] - v;                   // exclusive block offsets
}

__global__ __launch_bounds__(512) void scan3(int* __restrict__ out, const int* __restrict__ bsum, int nout) {
    int i = blockIdx.x * 512 + threadIdx.x;
    if (i < nout) out[i] += bsum[blockIdx.x];
}

__global__ void edge_fill(const int* __restrict__ rows, const int* __restrict__ cols,
                          const float* __restrict__ vals, int* __restrict__ cur,
                          int* __restrict__ ocol, float* __restrict__ oval, int E) {
    int i = blockIdx.x * 256 + threadIdx.x;
    if (i < E) {
        int r = rows[i];
        int p = atomicAdd(&cur[r], 1);
        ocol[p] = cols[i];
        oval[p] = vals[i];
    }
}

// ------------- W -> MFMA B-fragment order, bf16 hi/lo (Dekker) -------------
// frag element index o = ((kh*8 + nc)*64 + lane)*8 + j
//   col = nc*16 + (lane&15); k = kh*32 + (lane>>4)*8 + j;  value = W[k][col] (W row-major [K][128])
__global__ void prep_frag(const float* __restrict__ W, unsigned short* __restrict__ Fh,
                          unsigned short* __restrict__ Fl, int K) {
    int o = blockIdx.x * 256 + threadIdx.x;
    if (o >= K * 128) return;
    int j = o & 7;
    int lane = (o >> 3) & 63;
    int blk = o >> 9;                 // kh*8 + nc
    int nc = blk & 7, kh = blk >> 3;
    int col = nc * 16 + (lane & 15);
    int k = kh * 32 + (lane >> 4) * 8 + j;
    float f = W[k * 128 + col];
    __bf16 h = (__bf16)f;
    __bf16 l = (__bf16)(f - (float)h);
    Fh[o] = __builtin_bit_cast(unsigned short, h);
    Fl[o] = __builtin_bit_cast(unsigned short, l);
}

// ------------------------- SpMM + bias + LeakyReLU -------------------------
// one wave per output row; lane owns float2 at columns {2*lane, 2*lane+1}
__global__ __launch_bounds__(256) void spmm_lrelu(const int* __restrict__ ptr, const int* __restrict__ cols,
                                                  const float* __restrict__ vals, const float* __restrict__ x,
                                                  const float* __restrict__ bias, float* __restrict__ out,
                                                  int nrows) {
    int w = (blockIdx.x << 2) + (threadIdx.x >> 6);
    if (w >= nrows) return;
    int lane = threadIdx.x & 63;
    int s = ptr[w], e = ptr[w + 1];
    const float2* __restrict__ x2 = (const float2*)x;
    float ax = 0.f, ay = 0.f;
    int i = s;
    for (; i + 3 < e; i += 4) {
        int c0 = cols[i], c1 = cols[i + 1], c2 = cols[i + 2], c3 = cols[i + 3];
        float v0 = vals[i], v1 = vals[i + 1], v2 = vals[i + 2], v3 = vals[i + 3];
        float2 g0 = x2[(size_t)c0 * 64 + lane];
        float2 g1 = x2[(size_t)c1 * 64 + lane];
        float2 g2 = x2[(size_t)c2 * 64 + lane];
        float2 g3 = x2[(size_t)c3 * 64 + lane];
        ax += v0 * g0.x + v1 * g1.x + v2 * g2.x + v3 * g3.x;
        ay += v0 * g0.y + v1 * g1.y + v2 * g2.y + v3 * g3.y;
    }
    for (; i < e; i++) {
        int c = cols[i]; float v = vals[i];
        float2 g = x2[(size_t)c * 64 + lane];
        ax += v * g.x; ay += v * g.y;
    }
    float2 b2 = ((const float2*)bias)[lane];
    ax += b2.x; ay += b2.y;
    ax = ax >= 0.f ? ax : LRELU_ALPHA * ax;
    ay = ay >= 0.f ? ay : LRELU_ALPHA * ay;
    float2 o; o.x = ax; o.y = ay;
    ((float2*)out)[(size_t)w * 64 + lane] = o;
}

// --------------- register-fragment MFMA GEMM, N = 128, split-bf16 ---------------
// C[M,128] = A[M,K] @ W[K,128]; zero LDS, zero barriers.
// Each 256-thread block = 4 waves; wave owns 32 rows (2 row-fragments).
// Per 32-k phase: A loaded straight from global (f32 -> hi/lo bf16 in reg),
// B fragments read from pre-swizzled global buffers (16B/lane, L1/L2-resident).
// acc += Ahi*Whi + Ahi*Wlo + Alo*Whi   (drops ~2^-18 term)
// KPH = K/32 (4 or 8). KPH==8: A = [A1 | A2] concat on K (128+128).
// EPI: 0 raw store, 1 +bias, 2 +bias then z = noise*exp(0.1+0.9*softplus(logstd)) + mean
//      (logstd read in-place from C)
template <int KPH, int EPI>
__global__ __launch_bounds__(256) void gemm_reg(const float* __restrict__ A1, const float* __restrict__ A2,
                                                const unsigned short* __restrict__ Fh,
                                                const unsigned short* __restrict__ Fl,
                                                const float* __restrict__ bias,
                                                const float* __restrict__ noise,
                                                float* __restrict__ C, int M) {
    const int t = threadIdx.x;
    const int lane = t & 63;
    const int w = t >> 6;
    const int l15 = lane & 15, l4 = lane >> 4;
    const int row0 = blockIdx.x * 128 + w * 32;

    f32x4 acc[2][8] = {};

#pragma unroll
    for (int kh = 0; kh < KPH; kh++) {
        const float* Asrc;
        int kk;
        if constexpr (KPH == 8) {
            Asrc = (kh < 4) ? A1 : A2;
            kk = (kh & 3) * 32 + l4 * 8;
        } else {
            Asrc = A1;
            kk = kh * 32 + l4 * 8;
        }
        bf16x8 ah[2], al[2];
#pragma unroll
        for (int mr = 0; mr < 2; mr++) {
            int r = row0 + mr * 16 + l15;
            float4 f0, f1;
            if (r < M) {
                const float* p = Asrc + (size_t)r * 128 + kk;
                f0 = *(const float4*)p;
                f1 = *(const float4*)(p + 4);
            } else {
                f0 = make_float4(0.f, 0.f, 0.f, 0.f);
                f1 = f0;
            }
            float fv[8] = {f0.x, f0.y, f0.z, f0.w, f1.x, f1.y, f1.z, f1.w};
#pragma unroll
            for (int j = 0; j < 8; j++) {
                __bf16 h = (__bf16)fv[j];
                ah[mr][j] = h;
                al[mr][j] = (__bf16)(fv[j] - (float)h);
            }
        }
        const unsigned short* bh_base = Fh + (size_t)kh * 4096;   // 8 nc * 64 lanes * 8
        const unsigned short* bl_base = Fl + (size_t)kh * 4096;
#pragma unroll
        for (int nc = 0; nc < 8; nc++) {
            bf16x8 bh = *(const bf16x8*)(bh_base + nc * 512 + lane * 8);
            bf16x8 bl = *(const bf16x8*)(bl_base + nc * 512 + lane * 8);
#pragma unroll
            for (int mr = 0; mr < 2; mr++) {
                acc[mr][nc] = __builtin_amdgcn_mfma_f32_16x16x32_bf16(ah[mr], bh, acc[mr][nc], 0, 0, 0);
                acc[mr][nc] = __builtin_amdgcn_mfma_f32_16x16x32_bf16(ah[mr], bl, acc[mr][nc], 0, 0, 0);
                acc[mr][nc] = __builtin_amdgcn_mfma_f32_16x16x32_bf16(al[mr], bh, acc[mr][nc], 0, 0, 0);
            }
        }
    }

    // epilogue: C/D layout col = lane&15, row = (lane>>4)*4 + reg
#pragma unroll
    for (int mr = 0; mr < 2; mr++) {
        int rowb = row0 + mr * 16 + l4 * 4;
#pragma unroll
        for (int nc = 0; nc < 8; nc++) {
            int col = nc * 16 + l15;
#pragma unroll
            for (int j = 0; j < 4; j++) {
                int r = rowb + j;
                if (r < M) {
                    float v = acc[mr][nc][j];
                    if constexpr (EPI == 0) {
                        C[(size_t)r * 128 + col] = v;
                    } else if constexpr (EPI == 1) {
                        C[(size_t)r * 128 + col] = v + bias[col];
                    } else {
                        float mean = v + bias[col];
                        float ls = C[(size_t)r * 128 + col];
                        float sp = ls > 0.f ? ls + log1pf(expf(-ls)) : log1pf(expf(ls));
                        float sg = expf(0.1f + 0.9f * sp);
                        C[(size_t)r * 128 + col] = noise[(size_t)r * 128 + col] * sg + mean;
                    }
                }
            }
        }
    }
}

// ------------------------- launcher -------------------------
extern "C" void kernel_launch(void* const* d_in, const int* in_sizes, int n_in,
                              void* d_out, int out_size, void* d_ws, size_t ws_size,
                              hipStream_t stream) {
    const float* ufea    = (const float*)d_in[0];
    const float* vfea    = (const float*)d_in[1];
    const int*   uv_rows = (const int*)d_in[2];
    const int*   uv_cols = (const int*)d_in[3];
    const float* uv_vals = (const float*)d_in[4];
    const int*   vu_rows = (const int*)d_in[5];
    const int*   vu_cols = (const int*)d_in[6];
    const float* vu_vals = (const float*)d_in[7];
    const float* noise_u = (const float*)d_in[8];
    const float* noise_v = (const float*)d_in[9];
    const float* gc1_W  = (const float*)d_in[10];
    const float* gc1_b  = (const float*)d_in[11];
    const float* gc3m_W = (const float*)d_in[12];
    const float* gc3m_b = (const float*)d_in[13];
    const float* gc3s_W = (const float*)d_in[14];
    const float* gc3s_b = (const float*)d_in[15];
    const float* um_W = (const float*)d_in[16];
    const float* um_b = (const float*)d_in[17];
    const float* us_W = (const float*)d_in[18];
    const float* us_b = (const float*)d_in[19];
    const float* im_W = (const float*)d_in[20];
    const float* im_b = (const float*)d_in[21];
    const float* is_W = (const float*)d_in[22];
    const float* is_b = (const float*)d_in[23];

    const int H  = in_sizes[11];          // 128
    const int D  = in_sizes[10] / H;      // 128
    const int NU = in_sizes[0] / D;       // 100000
    const int NV = in_sizes[1] / D;       // 50000
    const int E  = in_sizes[2];           // 1600000

    // workspace layout
    char* ws = (char*)d_ws;
    size_t off = 0;
    auto alloc = [&](size_t bytes) -> char* {
        char* p = ws + off;
        off = (off + bytes + 255) & ~(size_t)255;
        return p;
    };
    unsigned short* wf_gc1_h  = (unsigned short*)alloc(128 * 128 * 2);
    unsigned short* wf_gc1_l  = (unsigned short*)alloc(128 * 128 * 2);
    unsigned short* wf_gc3m_h = (unsigned short*)alloc(128 * 128 * 2);
    unsigned short* wf_gc3m_l = (unsigned short*)alloc(128 * 128 * 2);
    unsigned short* wf_gc3s_h = (unsigned short*)alloc(128 * 128 * 2);
    unsigned short* wf_gc3s_l = (unsigned short*)alloc(128 * 128 * 2);
    unsigned short* wf_um_h = (unsigned short*)alloc(256 * 128 * 2);
    unsigned short* wf_um_l = (unsigned short*)alloc(256 * 128 * 2);
    unsigned short* wf_us_h = (unsigned short*)alloc(256 * 128 * 2);
    unsigned short* wf_us_l = (unsigned short*)alloc(256 * 128 * 2);
    unsigned short* wf_im_h = (unsigned short*)alloc(256 * 128 * 2);
    unsigned short* wf_im_l = (unsigned short*)alloc(256 * 128 * 2);
    unsigned short* wf_is_h = (unsigned short*)alloc(256 * 128 * 2);
    unsigned short* wf_is_l = (unsigned short*)alloc(256 * 128 * 2);
    int*   ptr_uv = (int*)alloc((size_t)(NU + 1) * 4);
    int*   cur_uv = (int*)alloc((size_t)NU * 4);
    int*   col_uv = (int*)alloc((size_t)E * 4);
    float* val_uv = (float*)alloc((size_t)E * 4);
    int*   ptr_vu = (int*)alloc((size_t)(NV + 1) * 4);
    int*   cur_vu = (int*)alloc((size_t)NV * 4);
    int*   col_vu = (int*)alloc((size_t)E * 4);
    float* val_vu = (float*)alloc((size_t)E * 4);
    int*   bsum   = (int*)alloc(1024 * 4);
    float* bufA = (float*)alloc((size_t)NU * 128 * 4);
    float* bufB = (float*)alloc((size_t)NU * 128 * 4);

    float* outU = (float*)d_out;
    float* outI = outU + (size_t)NU * H;

    const int eb = (E + 255) / 256;
    const int nbU = (NU + 1 + 511) / 512;
    const int nbV = (NV + 1 + 511) / 512;
    const int gU = (NU + 127) / 128, gV = (NV + 127) / 128;
    const int sU = (NU + 3) / 4, sV = (NV + 3) / 4;

    // ---- CSR build (both adjacencies) ----
    hipMemsetAsync(cur_uv, 0, (size_t)NU * 4, stream);
    hipMemsetAsync(cur_vu, 0, (size_t)NV * 4, stream);
    edge_count<<<eb, 256, 0, stream>>>(uv_rows, cur_uv, E);
    edge_count<<<eb, 256, 0, stream>>>(vu_rows, cur_vu, E);
    scan1<<<nbU, 512, 0, stream>>>(cur_uv, ptr_uv, bsum, NU, NU + 1);
    scan2<<<1, 256, 0, stream>>>(bsum, nbU);
    scan3<<<nbU, 512, 0, stream>>>(ptr_uv, bsum, NU + 1);
    scan1<<<nbV, 512, 0, stream>>>(cur_vu, ptr_vu, bsum, NV, NV + 1);
    scan2<<<1, 256, 0, stream>>>(bsum, nbV);
    scan3<<<nbV, 512, 0, stream>>>(ptr_vu, bsum, NV + 1);
    hipMemcpyAsync(cur_uv, ptr_uv, (size_t)NU * 4, hipMemcpyDeviceToDevice, stream);
    hipMemcpyAsync(cur_vu, ptr_vu, (size_t)NV * 4, hipMemcpyDeviceToDevice, stream);
    edge_fill<<<eb, 256, 0, stream>>>(uv_rows, uv_cols, uv_vals, cur_uv, col_uv, val_uv, E);
    edge_fill<<<eb, 256, 0, stream>>>(vu_rows, vu_cols, vu_vals, cur_vu, col_vu, val_vu, E);

    // ---- weights: swizzle to B-fragment order + bf16 hi/lo split ----
    prep_frag<<<64, 256, 0, stream>>>(gc1_W, wf_gc1_h, wf_gc1_l, 128);
    prep_frag<<<64, 256, 0, stream>>>(gc3m_W, wf_gc3m_h, wf_gc3m_l, 128);
    prep_frag<<<64, 256, 0, stream>>>(gc3s_W, wf_gc3s_h, wf_gc3s_l, 128);
    prep_frag<<<128, 256, 0, stream>>>(um_W, wf_um_h, wf_um_l, 256);
    prep_frag<<<128, 256, 0, stream>>>(us_W, wf_us_h, wf_us_l, 256);
    prep_frag<<<128, 256, 0, stream>>>(im_W, wf_im_h, wf_im_l, 256);
    prep_frag<<<128, 256, 0, stream>>>(is_W, wf_is_h, wf_is_l, 256);

    // ---- user path ----
    gemm_reg<4, 0><<<gU, 256, 0, stream>>>(ufea, nullptr, wf_gc1_h, wf_gc1_l, nullptr, nullptr, bufA, NU);
    spmm_lrelu<<<sV, 256, 0, stream>>>(ptr_vu, col_vu, val_vu, bufA, gc1_b, bufB, NV);          // user_ho [NV]
    gemm_reg<4, 0><<<gV, 256, 0, stream>>>(bufB, nullptr, wf_gc3s_h, wf_gc3s_l, nullptr, nullptr, bufA, NV);
    spmm_lrelu<<<sU, 256, 0, stream>>>(ptr_uv, col_uv, val_uv, bufA, gc3s_b, outU, NU);         // uhl -> d_out
    gemm_reg<8, 1><<<gU, 256, 0, stream>>>(outU, ufea, wf_us_h, wf_us_l, us_b, nullptr, outU, NU);   // user_logstd
    gemm_reg<4, 0><<<gV, 256, 0, stream>>>(bufB, nullptr, wf_gc3m_h, wf_gc3m_l, nullptr, nullptr, bufA, NV);
    spmm_lrelu<<<sU, 256, 0, stream>>>(ptr_uv, col_uv, val_uv, bufA, gc3m_b, bufB, NU);         // uhm [NU]
    gemm_reg<8, 2><<<gU, 256, 0, stream>>>(bufB, ufea, wf_um_h, wf_um_l, um_b, noise_u, outU, NU);   // user_z

    // ---- item path ----
    gemm_reg<4, 0><<<gV, 256, 0, stream>>>(vfea, nullptr, wf_gc1_h, wf_gc1_l, nullptr, nullptr, bufA, NV);
    spmm_lrelu<<<sU, 256, 0, stream>>>(ptr_uv, col_uv, val_uv, bufA, gc1_b, bufB, NU);          // item_ho [NU]
    gemm_reg<4, 0><<<gU, 256, 0, stream>>>(bufB, nullptr, wf_gc3s_h, wf_gc3s_l, nullptr, nullptr, bufA, NU);
    spmm_lrelu<<<sV, 256, 0, stream>>>(ptr_vu, col_vu, val_vu, bufA, gc3s_b, outI, NV);         // ihl -> d_out
    gemm_reg<8, 1><<<gV, 256, 0, stream>>>(outI, vfea, wf_is_h, wf_is_l, is_b, nullptr, outI, NV);   // item_logstd
    gemm_reg<4, 0><<<gU, 256, 0, stream>>>(bufB, nullptr, wf_gc3m_h, wf_gc3m_l, nullptr, nullptr, bufA, NU);
    spmm_lrelu<<<sV, 256, 0, stream>>>(ptr_vu, col_vu, val_vu, bufA, gc3m_b, bufB, NV);         // ihm [NV]
    gemm_reg<8, 2><<<gV, 256, 0, stream>>>(bufB, vfea, wf_im_h, wf_im_l, im_b, noise_v, outI, NV);   // item_z

    (void)n_in; (void)out_size; (void)ws_size;
}